// Round 5
// baseline (1386.984 us; speedup 1.0000x reference)
//
#include <hip/hip_runtime.h>

// ---------------------------------------------------------------------------
// LSTM autoencoder: B=32, F=128, T=2400, H=256, SEG=24, S=100.
//  - outer encoder: MFMA f16 16x16x32, W streamed from L2, triple-buffered
//    prefetch that stays in flight across lgkm-only barriers (no vmcnt drain).
//  - outer decoder: MFMA f16, W_hh + xw register-resident.
//  - inner encoder/decoder: weights register+LDS resident (1 block per seq)
//  - input projections precomputed as batched GEMMs with biases folded in
// ---------------------------------------------------------------------------

#define B_    32
#define F_    128
#define T_    2400
#define H_    256
#define SEG_  24
#define S_    100
#define NSEQ_ 3200

// workgroup barrier that drains LDS (lgkm) but leaves global loads/stores
// (vmcnt) in flight — __syncthreads() would emit s_waitcnt vmcnt(0).
#define BARRIER_LGKM() asm volatile("s_waitcnt lgkmcnt(0)\n\ts_barrier" ::: "memory")

using v2h = __attribute__((ext_vector_type(2))) _Float16;
using v4h = __attribute__((ext_vector_type(4))) _Float16;
using v8h = __attribute__((ext_vector_type(8))) _Float16;
using v4f = __attribute__((ext_vector_type(4))) float;

#ifndef __has_builtin
#define __has_builtin(x) 0
#endif

__device__ __forceinline__ float fdot2f(v2h a, v2h b, float c) {
#if __has_builtin(__builtin_amdgcn_fdot2)
  return __builtin_amdgcn_fdot2(a, b, c, false);
#else
  return c + (float)a[0] * (float)b[0] + (float)a[1] * (float)b[1];
#endif
}

// extract half2 pair e from a vector (constant-folds under #pragma unroll)
__device__ __forceinline__ v2h ext8(v8h v, int e) {
  v2h r; r[0] = v[2 * e]; r[1] = v[2 * e + 1]; return r;
}

__device__ __forceinline__ float sigm(float x) { return 1.f / (1.f + __expf(-x)); }
__device__ __forceinline__ float tanh_f(float x) { return 1.f - 2.f / (__expf(2.f * x) + 1.f); }

// ---------------------------------------------------------------------------
// Weight prep: build transposed half2 weights dst[k2][g] from row-major fp32
// [W_ih (G x K1); W_hh (G x K2src)] stacked along K. n = K2tot * G.
// ---------------------------------------------------------------------------
__global__ void k_wt2(v2h* __restrict__ dst, const float* __restrict__ w1, int K1,
                      const float* __restrict__ w2, int K2src, int G, int n) {
  int idx = blockIdx.x * 256 + threadIdx.x;
  if (idx >= n) return;
  int k2 = idx / G, g = idx - k2 * G;
  int k = 2 * k2;
  float v0, v1;
  if (k < K1) {
    v0 = w1[(size_t)g * K1 + k];
    v1 = w1[(size_t)g * K1 + k + 1];
  } else {
    int kk = k - K1;
    v0 = w2[(size_t)g * K2src + kk];
    v1 = w2[(size_t)g * K2src + kk + 1];
  }
  v2h r;
  r[0] = (_Float16)v0;
  r[1] = (_Float16)v1;
  dst[idx] = r;
}

// fp32 -> f16 elementwise (row-major weights for the inner kernels)
__global__ void k_f16(_Float16* __restrict__ dst, const float* __restrict__ src, int n) {
  int i = blockIdx.x * 256 + threadIdx.x;
  if (i < n) dst[i] = (_Float16)src[i];
}

// ---------------------------------------------------------------------------
// Outer-encoder W prepack into B-fragment-major layout:
// dst[((kc*64 + nt)*64 + lane)] = v8h { W[col][k0..k0+7] }, col = nt*16 +
// (lane&15), k0 = kc*32 + (lane>>4)*8.  12 k-chunks x 64 n-tiles.
// ---------------------------------------------------------------------------
__global__ void k_wpack_oe(v8h* __restrict__ dst, const float* __restrict__ wih,
                           const float* __restrict__ whh) {
  int idx = blockIdx.x * 256 + threadIdx.x;  // 0..49151
  if (idx >= 12 * 64 * 64) return;
  int lane = idx & 63;
  int nt = (idx >> 6) & 63;
  int kc = idx >> 12;
  int col = nt * 16 + (lane & 15);
  int k0 = kc * 32 + (lane >> 4) * 8;
  v8h r;
#pragma unroll
  for (int j = 0; j < 8; ++j) {
    int k = k0 + j;
    float v = (k < 128) ? wih[(size_t)col * 128 + k] : whh[(size_t)col * 256 + (k - 128)];
    r[j] = (_Float16)v;
  }
  dst[idx] = r;
}

// ---------------------------------------------------------------------------
// Outer-decoder W_hh prepack: 4 k-chunks x 32 n-tiles (G=512, K=128).
// ---------------------------------------------------------------------------
__global__ void k_wpack_od(v8h* __restrict__ dst, const float* __restrict__ whh) {
  int idx = blockIdx.x * 256 + threadIdx.x;  // 0..8191
  if (idx >= 4 * 32 * 64) return;
  int lane = idx & 63;
  int nt = (idx >> 6) & 31;
  int kc = idx >> 11;
  int col = nt * 16 + (lane & 15);
  int k0 = kc * 32 + (lane >> 4) * 8;
  v8h r;
#pragma unroll
  for (int j = 0; j < 8; ++j) r[j] = (_Float16)whh[(size_t)col * 128 + k0 + j];
  dst[idx] = r;
}

// ---------------------------------------------------------------------------
// Input transpose: inp (B,F,T) fp32 -> xT[(b*2400+tau)][f] f16  (tau = s*24+t)
// ---------------------------------------------------------------------------
__global__ void k_tin(const float* __restrict__ inp, _Float16* __restrict__ xT) {
  __shared__ float tile[32][33];
  int b = blockIdx.z, f0 = blockIdx.y * 32, t0 = blockIdx.x * 32;
  int tx = threadIdx.x, ty = threadIdx.y;
#pragma unroll
  for (int r = 0; r < 4; ++r) {
    int f = f0 + ty + 8 * r;
    tile[ty + 8 * r][tx] = inp[((size_t)b * F_ + f) * T_ + t0 + tx];
  }
  __syncthreads();
#pragma unroll
  for (int r = 0; r < 4; ++r) {
    int tau = t0 + ty + 8 * r;
    xT[((size_t)b * T_ + tau) * F_ + f0 + tx] = (_Float16)tile[tx][ty + 8 * r];
  }
}

// Output transpose: rec[(b*2400+tau)][f] fp32 -> out (B,F,T) fp32
__global__ void k_tout(const float* __restrict__ rec, float* __restrict__ out) {
  __shared__ float tile[32][33];
  int b = blockIdx.z, f0 = blockIdx.y * 32, t0 = blockIdx.x * 32;
  int tx = threadIdx.x, ty = threadIdx.y;
#pragma unroll
  for (int r = 0; r < 4; ++r) {
    int tau = t0 + ty + 8 * r;
    tile[ty + 8 * r][tx] = rec[((size_t)b * T_ + tau) * F_ + f0 + tx];
  }
  __syncthreads();
#pragma unroll
  for (int r = 0; r < 4; ++r) {
    int f = f0 + ty + 8 * r;
    out[((size_t)b * F_ + f) * T_ + t0 + tx] = tile[tx][ty + 8 * r];
  }
}

// ---------------------------------------------------------------------------
// Outer encoder, MFMA + pipelined B-stream. Grid 100 blocks x 512 threads.
// B (W) is periodic in t, so kc=10/11 prefetch next step's kc=0/1; the
// lgkm-only barriers keep those 16 loads in flight across the epilogue.
// Slot map: kc uses Bf[kc%3], loaded 2 kc-iterations earlier.
// ---------------------------------------------------------------------------
__global__ __launch_bounds__(512, 2) void k_outer_enc_mfma(
    const v8h* __restrict__ wpack,    // [12][64][64] v8h
    const _Float16* __restrict__ xT,  // [(seq*24+t)*128 + f]
    const float* __restrict__ bih, const float* __restrict__ bhh,
    float* __restrict__ cst) {        // [3200][256] fp32
  __shared__ __align__(16) _Float16 a2[32][392];
  const int tid = threadIdx.x;
  const int w = tid >> 6;
  const int lane = tid & 63;
  const int cI = lane & 15;
  const int q = lane >> 4;
  const int seq0 = blockIdx.x * 32;

  float bias[4][2];
#pragma unroll
  for (int g = 0; g < 4; ++g)
#pragma unroll
    for (int jt = 0; jt < 2; ++jt) {
      int col = g * 256 + w * 32 + jt * 16 + cI;
      bias[g][jt] = bih[col] + bhh[col];
    }

  for (int i = tid; i < 32 * 256; i += 512) a2[i >> 8][128 + (i & 255)] = (_Float16)0.f;
  {
    int row = tid >> 4, ch = tid & 15;
    v8h xv = ((const v8h*)(xT + ((size_t)(seq0 + row) * SEG_ + 0) * F_))[ch];
    *(v8h*)(&a2[row][ch * 8]) = xv;
  }
  __syncthreads();

  float cs[2][2][4];
#pragma unroll
  for (int mt = 0; mt < 2; ++mt)
#pragma unroll
    for (int jt = 0; jt < 2; ++jt)
#pragma unroll
      for (int r = 0; r < 4; ++r) cs[mt][jt][r] = 0.f;

  // fragment base for this wave/lane; n-tile for slot n: nt = (n>>1)*16 + w*2 + (n&1)
  const v8h* wp = wpack + lane;
  v8h Bf[3][8];
  // prologue: kc=0 -> slot0, kc=1 -> slot1
#pragma unroll
  for (int n = 0; n < 8; ++n) {
    int nt = (n >> 1) * 16 + w * 2 + (n & 1);
    Bf[0][n] = wp[(size_t)(0 * 64 + nt) * 64];
    Bf[1][n] = wp[(size_t)(1 * 64 + nt) * 64];
  }

  const int row = tid >> 4, ch = tid & 15;
  for (int t = 0; t < SEG_; ++t) {
    // issue next step's x load early so its vmcnt wait doesn't drain prefetch
    int tn = (t + 1 < SEG_) ? t + 1 : t;
    v8h xv = ((const v8h*)(xT + ((size_t)(seq0 + row) * SEG_ + tn) * F_))[ch];

    v4f C[2][8];
#pragma unroll
    for (int mt = 0; mt < 2; ++mt)
#pragma unroll
      for (int n = 0; n < 8; ++n) {
        v4f z = {0.f, 0.f, 0.f, 0.f};
        C[mt][n] = z;
      }
#pragma unroll
    for (int kc = 0; kc < 12; ++kc) {
      const int pf = (kc + 2) % 12;   // periodic in t: 10->0, 11->1 of next step
      const int spf = (kc + 2) % 3;
      const int scur = kc % 3;
#pragma unroll
      for (int n = 0; n < 8; ++n) {
        int nt = (n >> 1) * 16 + w * 2 + (n & 1);
        Bf[spf][n] = wp[(size_t)(pf * 64 + nt) * 64];
      }
      v8h A0 = *(const v8h*)(&a2[0 * 16 + cI][kc * 32 + q * 8]);
      v8h A1 = *(const v8h*)(&a2[1 * 16 + cI][kc * 32 + q * 8]);
#pragma unroll
      for (int n = 0; n < 8; ++n) {
        C[0][n] = __builtin_amdgcn_mfma_f32_16x16x32_f16(A0, Bf[scur][n], C[0][n], 0, 0, 0);
        C[1][n] = __builtin_amdgcn_mfma_f32_16x16x32_f16(A1, Bf[scur][n], C[1][n], 0, 0, 0);
      }
    }
    BARRIER_LGKM();  // a2 reads done; B prefetch stays in flight
#pragma unroll
    for (int mt = 0; mt < 2; ++mt)
#pragma unroll
      for (int jt = 0; jt < 2; ++jt)
#pragma unroll
        for (int r = 0; r < 4; ++r) {
          float gi = sigm(C[mt][0 * 2 + jt][r] + bias[0][jt]);
          float gf = sigm(C[mt][1 * 2 + jt][r] + bias[1][jt]);
          float gg = tanh_f(C[mt][2 * 2 + jt][r] + bias[2][jt]);
          float go = sigm(C[mt][3 * 2 + jt][r] + bias[3][jt]);
          float cc = gf * cs[mt][jt][r] + gi * gg;
          cs[mt][jt][r] = cc;
          float h = go * tanh_f(cc);
          a2[mt * 16 + q * 4 + r][128 + w * 32 + jt * 16 + cI] = (_Float16)h;
        }
    if (t < SEG_ - 1) *(v8h*)(&a2[row][ch * 8]) = xv;
    BARRIER_LGKM();  // h + x visible before next K-loop
  }
#pragma unroll
  for (int mt = 0; mt < 2; ++mt)
#pragma unroll
    for (int jt = 0; jt < 2; ++jt)
#pragma unroll
      for (int r = 0; r < 4; ++r)
        cst[(size_t)(seq0 + mt * 16 + q * 4 + r) * H_ + w * 32 + jt * 16 + cI] = cs[mt][jt][r];
}

// ---------------------------------------------------------------------------
// Outer decoder, MFMA. W_hh + xw register-resident; lgkm-only barriers let
// the per-step rec stores drain in the background.
// ---------------------------------------------------------------------------
__global__ __launch_bounds__(512, 2) void k_outer_dec_mfma(
    const v8h* __restrict__ wpack,  // [4][32][64] v8h
    const float* __restrict__ xw,   // [3200][512] (biases folded)
    float* __restrict__ rec) {      // [3200*24][128] fp32
  __shared__ __align__(16) _Float16 ah[32][136];
  const int tid = threadIdx.x;
  const int w = tid >> 6;
  const int lane = tid & 63;
  const int cI = lane & 15;
  const int q = lane >> 4;
  const int seq0 = blockIdx.x * 32;

  v8h Bf[4][4];  // [kc][g]
#pragma unroll
  for (int kc = 0; kc < 4; ++kc)
#pragma unroll
    for (int g = 0; g < 4; ++g)
      Bf[kc][g] = wpack[(size_t)(kc * 32 + g * 8 + w) * 64 + lane];

  float xwr[2][4][4];
#pragma unroll
  for (int mt = 0; mt < 2; ++mt)
#pragma unroll
    for (int r = 0; r < 4; ++r) {
      int row = seq0 + mt * 16 + q * 4 + r;
#pragma unroll
      for (int g = 0; g < 4; ++g)
        xwr[mt][r][g] = xw[(size_t)row * 512 + g * 128 + w * 16 + cI];
    }

  for (int i = tid; i < 32 * 128; i += 512) ah[i >> 7][i & 127] = (_Float16)0.f;
  __syncthreads();

  float cs[2][4];
#pragma unroll
  for (int mt = 0; mt < 2; ++mt)
#pragma unroll
    for (int r = 0; r < 4; ++r) cs[mt][r] = 0.f;

  for (int t = 0; t < SEG_; ++t) {
    v4f C[2][4];
#pragma unroll
    for (int mt = 0; mt < 2; ++mt)
#pragma unroll
      for (int g = 0; g < 4; ++g) {
        v4f z = {0.f, 0.f, 0.f, 0.f};
        C[mt][g] = z;
      }
#pragma unroll
    for (int kc = 0; kc < 4; ++kc) {
      v8h A0 = *(const v8h*)(&ah[0 * 16 + cI][kc * 32 + q * 8]);
      v8h A1 = *(const v8h*)(&ah[1 * 16 + cI][kc * 32 + q * 8]);
#pragma unroll
      for (int g = 0; g < 4; ++g) {
        C[0][g] = __builtin_amdgcn_mfma_f32_16x16x32_f16(A0, Bf[kc][g], C[0][g], 0, 0, 0);
        C[1][g] = __builtin_amdgcn_mfma_f32_16x16x32_f16(A1, Bf[kc][g], C[1][g], 0, 0, 0);
      }
    }
    BARRIER_LGKM();  // A reads done before h rewrite
#pragma unroll
    for (int mt = 0; mt < 2; ++mt)
#pragma unroll
      for (int r = 0; r < 4; ++r) {
        float gi = sigm(C[mt][0][r] + xwr[mt][r][0]);
        float gf = sigm(C[mt][1][r] + xwr[mt][r][1]);
        float gg = tanh_f(C[mt][2][r] + xwr[mt][r][2]);
        float go = sigm(C[mt][3][r] + xwr[mt][r][3]);
        float cc = gf * cs[mt][r] + gi * gg;
        cs[mt][r] = cc;
        float h = go * tanh_f(cc);
        int row = mt * 16 + q * 4 + r;
        ah[row][w * 16 + cI] = (_Float16)h;
        rec[((size_t)(seq0 + row) * SEG_ + t) * 128 + w * 16 + cI] = h;
      }
    BARRIER_LGKM();
  }
}

// ---------------------------------------------------------------------------
// Batched input projection: out[M][G] = A[M][256] @ wt2[128][G] + b1 + b2.
// ---------------------------------------------------------------------------
template <int GT>
__global__ __launch_bounds__(256) void k_proj(
    const float* __restrict__ A, const v2h* __restrict__ wt2,
    const float* __restrict__ b1, const float* __restrict__ b2,
    float* __restrict__ out) {
  constexpr int G = GT * 256;
  __shared__ __align__(16) _Float16 a2[16][256];
  const int tid = threadIdx.x;
  const size_t row0 = (size_t)blockIdx.x * 16;
  for (int idx = tid; idx < 16 * 256; idx += 256) {
    int r = idx >> 8, k = idx & 255;
    a2[r][k] = (_Float16)A[(row0 + (size_t)r) * 256 + k];
  }
  __syncthreads();
  float acc[16][GT];
#pragma unroll
  for (int r = 0; r < 16; ++r)
#pragma unroll
    for (int q = 0; q < GT; ++q) acc[r][q] = 0.f;
  const v2h* wp = wt2 + tid;
#pragma unroll 2
  for (int k2 = 0; k2 < 128; ++k2) {
    v2h w[GT];
#pragma unroll
    for (int q = 0; q < GT; ++q) w[q] = wp[256 * q];
    wp += G;
#pragma unroll
    for (int r = 0; r < 16; ++r) {
      v2h a = ((const v2h*)&a2[r][0])[k2];
#pragma unroll
      for (int q = 0; q < GT; ++q) acc[r][q] = fdot2f(w[q], a, acc[r][q]);
    }
  }
#pragma unroll
  for (int q = 0; q < GT; ++q) {
    float bias = b1[tid + 256 * q] + b2[tid + 256 * q];
#pragma unroll
    for (int r = 0; r < 16; ++r)
      out[(row0 + (size_t)r) * G + tid + 256 * q] = acc[r][q] + bias;
  }
}

// ---------------------------------------------------------------------------
// Inner LSTM (encoder/decoder): 1 block per batch element, 512 threads.
// Thread pair (2p,2p+1) owns h-index p; 3 gate rows in VGPRs, o-row in LDS
// (b128 reads). lgkm-only barriers; constant-input case hoists xw.
// ---------------------------------------------------------------------------
__global__ __launch_bounds__(512) void k_inner(
    const _Float16* __restrict__ whh,  // [1024][256] row-major f16
    const float* __restrict__ xw, long xw_seq_stride, long xw_t_stride, int T,
    float* __restrict__ h_out,   // [B*T][256] or nullptr
    float* __restrict__ c_out) { // [B][256] or nullptr
  __shared__ __align__(16) _Float16 ah[H_];
  __shared__ __align__(16) _Float16 wo[H_][264];  // 528B rows (16B-aligned)
  const int t_ = threadIdx.x;
  const int p = t_ >> 1;
  const int hf = t_ & 1;
  const int b = blockIdx.x;

  v8h wv[3][16];
#pragma unroll
  for (int r = 0; r < 3; ++r) {
    const v8h* src = (const v8h*)(whh + ((size_t)(H_ * r + p)) * H_ + hf * 128);
#pragma unroll
    for (int q = 0; q < 16; ++q) wv[r][q] = src[q];
  }
  {
    const v8h* src = (const v8h*)(whh + ((size_t)(H_ * 3 + p)) * H_ + hf * 128);
    v8h* dst = (v8h*)&wo[p][hf * 128];
#pragma unroll
    for (int q = 0; q < 16; ++q) dst[q] = src[q];
  }
  if (t_ < H_) ah[t_] = (_Float16)0.f;
  float c = 0.f;
  __syncthreads();

  const bool cx = (xw_t_stride == 0);
  float x0 = 0.f, x1 = 0.f, x2 = 0.f, x3 = 0.f;
  if (cx) {
    const float* xwp = xw + (size_t)b * xw_seq_stride;
    x0 = xwp[p]; x1 = xwp[H_ + p]; x2 = xwp[2 * H_ + p]; x3 = xwp[3 * H_ + p];
  }

  for (int t = 0; t < T; ++t) {
    if (!cx) {
      const float* xwp = xw + (size_t)b * xw_seq_stride + (size_t)t * xw_t_stride;
      x0 = xwp[p]; x1 = xwp[H_ + p]; x2 = xwp[2 * H_ + p]; x3 = xwp[3 * H_ + p];
    }
    float a0 = 0.f, a1 = 0.f, a2 = 0.f, a3 = 0.f;
    const v8h* A8 = ((const v8h*)ah) + hf * 16;
    const v8h* O8 = (const v8h*)&wo[p][hf * 128];
#pragma unroll
    for (int q = 0; q < 16; ++q) {
      v8h av = A8[q];
      v8h ov = O8[q];
      v8h w0v = wv[0][q], w1v = wv[1][q], w2v = wv[2][q];
#pragma unroll
      for (int e = 0; e < 4; ++e) {
        v2h ap = ext8(av, e);
        a0 = fdot2f(ext8(w0v, e), ap, a0);
        a1 = fdot2f(ext8(w1v, e), ap, a1);
        a2 = fdot2f(ext8(w2v, e), ap, a2);
        a3 = fdot2f(ext8(ov, e), ap, a3);
      }
    }
    a0 += __shfl_xor(a0, 1);
    a1 += __shfl_xor(a1, 1);
    a2 += __shfl_xor(a2, 1);
    a3 += __shfl_xor(a3, 1);
    float gi = sigm(a0 + x0);
    float gf = sigm(a1 + x1);
    float gg = tanh_f(a2 + x2);
    float go = sigm(a3 + x3);
    c = gf * c + gi * gg;
    float h = go * tanh_f(c);
    BARRIER_LGKM();
    if (hf == 0) {
      ah[p] = (_Float16)h;
      if (h_out) h_out[((size_t)b * T + t) * H_ + p] = h;
    }
    BARRIER_LGKM();
  }
  if (c_out && hf == 0) c_out[(size_t)b * H_ + p] = c;
}

// ---------------------------------------------------------------------------
extern "C" void kernel_launch(void* const* d_in, const int* in_sizes, int n_in,
                              void* d_out, int out_size, void* d_ws, size_t ws_size,
                              hipStream_t stream) {
  const float* inp    = (const float*)d_in[0];
  const float* oe_wih = (const float*)d_in[1];
  const float* oe_whh = (const float*)d_in[2];
  const float* oe_bih = (const float*)d_in[3];
  const float* oe_bhh = (const float*)d_in[4];
  const float* ie_wih = (const float*)d_in[5];
  const float* ie_whh = (const float*)d_in[6];
  const float* ie_bih = (const float*)d_in[7];
  const float* ie_bhh = (const float*)d_in[8];
  const float* id_wih = (const float*)d_in[9];
  const float* id_whh = (const float*)d_in[10];
  const float* id_bih = (const float*)d_in[11];
  const float* id_bhh = (const float*)d_in[12];
  const float* od_wih = (const float*)d_in[13];
  const float* od_whh = (const float*)d_in[14];
  const float* od_bih = (const float*)d_in[15];
  const float* od_bhh = (const float*)d_in[16];

  char* ws = (char*)d_ws;
  _Float16* xT     = (_Float16*)(ws + 0);         // 76800*128 f16 = 19,660,800
  v8h* wpack_oe    = (v8h*)(ws + 19660800);       // 12*64*64*16  =    786,432
  float* cst       = (float*)(ws + 20447232);     // 3200*256*4   =  3,276,800
  v2h* wt2_ie      = (v2h*)(ws + 23724032);       // 128*1024*4   =    524,288
  float* xw_ie     = (float*)(ws + 24248320);     // 3200*1024*4  = 13,107,200
  _Float16* whh_ie = (_Float16*)(ws + 37355520);  // 262144 f16   =    524,288
  float* bott      = (float*)(ws + 37879808);     // 32*256*4     =     32,768
  v2h* wt2_id      = (v2h*)(ws + 37912576);       //              =    524,288
  float* xw_id     = (float*)(ws + 38436864);     // 32*1024*4    =    131,072
  _Float16* whh_id = (_Float16*)(ws + 38567936);  //              =    524,288
  float* dec       = (float*)(ws + 39092224);     // 3200*256*4   =  3,276,800
  v2h* wt2_odih    = (v2h*)(ws + 42369024);       // 128*512*4    =    262,144
  float* xw_od     = (float*)(ws + 42631168);     // 3200*512*4   =  6,553,600
  v8h* wpack_od    = (v8h*)(ws + 49184768);       // 4*32*64*16   =    131,072
  float* rec       = (float*)(ws + 49315840);     // 76800*128*4  = 39,321,600  (end 88.6 MB)

  // --- weight prep ---
  k_wpack_oe<<<dim3(192), dim3(256), 0, stream>>>(wpack_oe, oe_wih, oe_whh);
  k_wt2<<<dim3(512), dim3(256), 0, stream>>>(wt2_ie, ie_wih, 256, nullptr, 0, 1024, 128 * 1024);
  k_wt2<<<dim3(512), dim3(256), 0, stream>>>(wt2_id, id_wih, 256, nullptr, 0, 1024, 128 * 1024);
  k_wt2<<<dim3(256), dim3(256), 0, stream>>>(wt2_odih, od_wih, 256, nullptr, 0, 512, 128 * 512);
  k_wpack_od<<<dim3(32), dim3(256), 0, stream>>>(wpack_od, od_whh);
  k_f16<<<dim3(1024), dim3(256), 0, stream>>>(whh_ie, ie_whh, 262144);
  k_f16<<<dim3(1024), dim3(256), 0, stream>>>(whh_id, id_whh, 262144);

  // --- pipeline ---
  k_tin<<<dim3(75, 4, 32), dim3(32, 8), 0, stream>>>(inp, xT);
  k_outer_enc_mfma<<<dim3(100), dim3(512), 0, stream>>>(wpack_oe, xT, oe_bih, oe_bhh, cst);
  k_proj<4><<<dim3(200), dim3(256), 0, stream>>>(cst, wt2_ie, ie_bih, ie_bhh, xw_ie);
  k_inner<<<dim3(32), dim3(512), 0, stream>>>(whh_ie, xw_ie, (long)S_ * 1024, 1024, S_, nullptr, bott);
  k_proj<4><<<dim3(2), dim3(256), 0, stream>>>(bott, wt2_id, id_bih, id_bhh, xw_id);
  k_inner<<<dim3(32), dim3(512), 0, stream>>>(whh_id, xw_id, 1024, 0, S_, dec, nullptr);
  k_proj<2><<<dim3(200), dim3(256), 0, stream>>>(dec, wt2_odih, od_bih, od_bhh, xw_od);
  k_outer_dec_mfma<<<dim3(100), dim3(512), 0, stream>>>(wpack_od, xw_od, rec);
  k_tout<<<dim3(75, 4, 32), dim3(32, 8), 0, stream>>>(rec, (float*)d_out);

  (void)in_sizes; (void)n_in; (void)out_size; (void)ws_size;
}

// Round 6
// 1326.774 us; speedup vs baseline: 1.0454x; 1.0454x over previous
//
#include <hip/hip_runtime.h>

// ---------------------------------------------------------------------------
// LSTM autoencoder: B=32, F=128, T=2400, H=256, SEG=24, S=100.
//  - outer encoder: MFMA f16 16x16x32, W streamed from L2, double-buffered B
//    with cross-step depth-1 prefetch surviving lgkm-only barriers; A-tile
//    double-buffered in LDS -> 1 barrier/step; c-state in VGPRs.
//  - outer decoder: MFMA f16, W_hh + xw register-resident, 1 barrier/step.
//  - inner encoder/decoder: weights in VGPRs (i,f,g + half of o) + half of o
//    in LDS; double-buffered h -> 1 barrier/step. LDS-issue-bound by design.
//  - input projections precomputed as batched GEMMs with biases folded in
// ---------------------------------------------------------------------------

#define B_    32
#define F_    128
#define T_    2400
#define H_    256
#define SEG_  24
#define S_    100
#define NSEQ_ 3200

// workgroup barrier that drains LDS (lgkm) but leaves global loads/stores
// (vmcnt) in flight — __syncthreads() would emit s_waitcnt vmcnt(0).
#define BARRIER_LGKM() asm volatile("s_waitcnt lgkmcnt(0)\n\ts_barrier" ::: "memory")

using v2h = __attribute__((ext_vector_type(2))) _Float16;
using v4h = __attribute__((ext_vector_type(4))) _Float16;
using v8h = __attribute__((ext_vector_type(8))) _Float16;
using v4f = __attribute__((ext_vector_type(4))) float;

#ifndef __has_builtin
#define __has_builtin(x) 0
#endif

__device__ __forceinline__ float fdot2f(v2h a, v2h b, float c) {
#if __has_builtin(__builtin_amdgcn_fdot2)
  return __builtin_amdgcn_fdot2(a, b, c, false);
#else
  return c + (float)a[0] * (float)b[0] + (float)a[1] * (float)b[1];
#endif
}

// extract half2 pair e from a vector (constant-folds under #pragma unroll)
__device__ __forceinline__ v2h ext8(v8h v, int e) {
  v2h r; r[0] = v[2 * e]; r[1] = v[2 * e + 1]; return r;
}

__device__ __forceinline__ float sigm(float x) { return 1.f / (1.f + __expf(-x)); }
__device__ __forceinline__ float tanh_f(float x) { return 1.f - 2.f / (__expf(2.f * x) + 1.f); }

// ---------------------------------------------------------------------------
// Weight prep: transposed half2 weights dst[k2][g] from row-major fp32.
// ---------------------------------------------------------------------------
__global__ void k_wt2(v2h* __restrict__ dst, const float* __restrict__ w1, int K1,
                      const float* __restrict__ w2, int K2src, int G, int n) {
  int idx = blockIdx.x * 256 + threadIdx.x;
  if (idx >= n) return;
  int k2 = idx / G, g = idx - k2 * G;
  int k = 2 * k2;
  float v0, v1;
  if (k < K1) {
    v0 = w1[(size_t)g * K1 + k];
    v1 = w1[(size_t)g * K1 + k + 1];
  } else {
    int kk = k - K1;
    v0 = w2[(size_t)g * K2src + kk];
    v1 = w2[(size_t)g * K2src + kk + 1];
  }
  v2h r;
  r[0] = (_Float16)v0;
  r[1] = (_Float16)v1;
  dst[idx] = r;
}

// fp32 -> f16 elementwise (row-major weights for the inner kernels)
__global__ void k_f16(_Float16* __restrict__ dst, const float* __restrict__ src, int n) {
  int i = blockIdx.x * 256 + threadIdx.x;
  if (i < n) dst[i] = (_Float16)src[i];
}

// ---------------------------------------------------------------------------
// Outer-encoder W prepack into B-fragment-major layout. 12 kc x 64 nt.
// ---------------------------------------------------------------------------
__global__ void k_wpack_oe(v8h* __restrict__ dst, const float* __restrict__ wih,
                           const float* __restrict__ whh) {
  int idx = blockIdx.x * 256 + threadIdx.x;  // 0..49151
  if (idx >= 12 * 64 * 64) return;
  int lane = idx & 63;
  int nt = (idx >> 6) & 63;
  int kc = idx >> 12;
  int col = nt * 16 + (lane & 15);
  int k0 = kc * 32 + (lane >> 4) * 8;
  v8h r;
#pragma unroll
  for (int j = 0; j < 8; ++j) {
    int k = k0 + j;
    float v = (k < 128) ? wih[(size_t)col * 128 + k] : whh[(size_t)col * 256 + (k - 128)];
    r[j] = (_Float16)v;
  }
  dst[idx] = r;
}

// ---------------------------------------------------------------------------
// Outer-decoder W_hh prepack: 4 kc x 32 nt (G=512, K=128).
// ---------------------------------------------------------------------------
__global__ void k_wpack_od(v8h* __restrict__ dst, const float* __restrict__ whh) {
  int idx = blockIdx.x * 256 + threadIdx.x;  // 0..8191
  if (idx >= 4 * 32 * 64) return;
  int lane = idx & 63;
  int nt = (idx >> 6) & 31;
  int kc = idx >> 11;
  int col = nt * 16 + (lane & 15);
  int k0 = kc * 32 + (lane >> 4) * 8;
  v8h r;
#pragma unroll
  for (int j = 0; j < 8; ++j) r[j] = (_Float16)whh[(size_t)col * 128 + k0 + j];
  dst[idx] = r;
}

// ---------------------------------------------------------------------------
// Input transpose: inp (B,F,T) fp32 -> xT[(b*2400+tau)][f] f16
// ---------------------------------------------------------------------------
__global__ void k_tin(const float* __restrict__ inp, _Float16* __restrict__ xT) {
  __shared__ float tile[32][33];
  int b = blockIdx.z, f0 = blockIdx.y * 32, t0 = blockIdx.x * 32;
  int tx = threadIdx.x, ty = threadIdx.y;
#pragma unroll
  for (int r = 0; r < 4; ++r) {
    int f = f0 + ty + 8 * r;
    tile[ty + 8 * r][tx] = inp[((size_t)b * F_ + f) * T_ + t0 + tx];
  }
  __syncthreads();
#pragma unroll
  for (int r = 0; r < 4; ++r) {
    int tau = t0 + ty + 8 * r;
    xT[((size_t)b * T_ + tau) * F_ + f0 + tx] = (_Float16)tile[tx][ty + 8 * r];
  }
}

// Output transpose: rec[(b*2400+tau)][f] fp32 -> out (B,F,T) fp32
__global__ void k_tout(const float* __restrict__ rec, float* __restrict__ out) {
  __shared__ float tile[32][33];
  int b = blockIdx.z, f0 = blockIdx.y * 32, t0 = blockIdx.x * 32;
  int tx = threadIdx.x, ty = threadIdx.y;
#pragma unroll
  for (int r = 0; r < 4; ++r) {
    int tau = t0 + ty + 8 * r;
    tile[ty + 8 * r][tx] = rec[((size_t)b * T_ + tau) * F_ + f0 + tx];
  }
  __syncthreads();
#pragma unroll
  for (int r = 0; r < 4; ++r) {
    int f = f0 + ty + 8 * r;
    out[((size_t)b * F_ + f) * T_ + t0 + tx] = tile[tx][ty + 8 * r];
  }
}

// ---------------------------------------------------------------------------
// Outer encoder, MFMA. 100 blocks x 512 threads (8 waves), M=32 seqs.
// B double-buffered (Bf[2][8]); prefetch (kc+1)%12 into slot (kc+1)&1 — at
// kc=11 this loads next step's kc=0, kept in flight across the lgkm-only
// barrier. A-tile double-buffered in LDS -> single barrier per step.
// ---------------------------------------------------------------------------
__global__ __launch_bounds__(512, 2) void k_outer_enc_mfma(
    const v8h* __restrict__ wpack,    // [12][64][64] v8h
    const _Float16* __restrict__ xT,  // [(seq*24+t)*128 + f]
    const float* __restrict__ bih, const float* __restrict__ bhh,
    float* __restrict__ cst) {        // [3200][256] fp32
  __shared__ __align__(16) _Float16 a2[2][32][392];
  const int tid = threadIdx.x;
  const int w = tid >> 6;
  const int lane = tid & 63;
  const int cI = lane & 15;
  const int q = lane >> 4;
  const int seq0 = blockIdx.x * 32;

  float bias[4][2];
#pragma unroll
  for (int g = 0; g < 4; ++g)
#pragma unroll
    for (int jt = 0; jt < 2; ++jt) {
      int col = g * 256 + w * 32 + jt * 16 + cI;
      bias[g][jt] = bih[col] + bhh[col];
    }

  for (int i = tid; i < 32 * 256; i += 512) a2[0][i >> 8][128 + (i & 255)] = (_Float16)0.f;
  const int row = tid >> 4, ch = tid & 15;
  {
    v8h xv = ((const v8h*)(xT + ((size_t)(seq0 + row) * SEG_ + 0) * F_))[ch];
    *(v8h*)(&a2[0][row][ch * 8]) = xv;
  }
  __syncthreads();

  float cs[2][2][4];
#pragma unroll
  for (int mt = 0; mt < 2; ++mt)
#pragma unroll
    for (int jt = 0; jt < 2; ++jt)
#pragma unroll
      for (int r = 0; r < 4; ++r) cs[mt][jt][r] = 0.f;

  const v8h* wp = wpack + lane;
  v8h Bf[2][8];
#pragma unroll
  for (int n = 0; n < 8; ++n) {  // prologue: kc=0 -> slot 0
    int nt = (n >> 1) * 16 + w * 2 + (n & 1);
    Bf[0][n] = wp[(size_t)(0 * 64 + nt) * 64];
  }

  for (int t = 0; t < SEG_; ++t) {
    const int cb = t & 1, nb = cb ^ 1;
    // next step's x load issued early (held in regs across the kc-loop)
    int tn = (t + 1 < SEG_) ? t + 1 : t;
    v8h xv = ((const v8h*)(xT + ((size_t)(seq0 + row) * SEG_ + tn) * F_))[ch];

    v4f C[2][8];
#pragma unroll
    for (int mt = 0; mt < 2; ++mt)
#pragma unroll
      for (int n = 0; n < 8; ++n) {
        v4f z = {0.f, 0.f, 0.f, 0.f};
        C[mt][n] = z;
      }
#pragma unroll
    for (int kc = 0; kc < 12; ++kc) {
      const int kn = (kc + 1) % 12;   // at kc=11: next step's kc=0
      const int sn = (kc + 1) & 1;
      const int sc = kc & 1;
#pragma unroll
      for (int n = 0; n < 8; ++n) {
        int nt = (n >> 1) * 16 + w * 2 + (n & 1);
        Bf[sn][n] = wp[(size_t)(kn * 64 + nt) * 64];
      }
      v8h A0 = *(const v8h*)(&a2[cb][0 * 16 + cI][kc * 32 + q * 8]);
      v8h A1 = *(const v8h*)(&a2[cb][1 * 16 + cI][kc * 32 + q * 8]);
#pragma unroll
      for (int n = 0; n < 8; ++n) {
        C[0][n] = __builtin_amdgcn_mfma_f32_16x16x32_f16(A0, Bf[sc][n], C[0][n], 0, 0, 0);
        C[1][n] = __builtin_amdgcn_mfma_f32_16x16x32_f16(A1, Bf[sc][n], C[1][n], 0, 0, 0);
      }
    }
    // epilogue writes go to the OTHER buffer -> no barrier needed before them
#pragma unroll
    for (int mt = 0; mt < 2; ++mt)
#pragma unroll
      for (int jt = 0; jt < 2; ++jt)
#pragma unroll
        for (int r = 0; r < 4; ++r) {
          float gi = sigm(C[mt][0 * 2 + jt][r] + bias[0][jt]);
          float gf = sigm(C[mt][1 * 2 + jt][r] + bias[1][jt]);
          float gg = tanh_f(C[mt][2 * 2 + jt][r] + bias[2][jt]);
          float go = sigm(C[mt][3 * 2 + jt][r] + bias[3][jt]);
          float cc = gf * cs[mt][jt][r] + gi * gg;
          cs[mt][jt][r] = cc;
          float h = go * tanh_f(cc);
          a2[nb][mt * 16 + q * 4 + r][128 + w * 32 + jt * 16 + cI] = (_Float16)h;
        }
    if (t < SEG_ - 1) *(v8h*)(&a2[nb][row][ch * 8]) = xv;
    BARRIER_LGKM();  // writes to nb visible before next iteration reads nb
  }
#pragma unroll
  for (int mt = 0; mt < 2; ++mt)
#pragma unroll
    for (int jt = 0; jt < 2; ++jt)
#pragma unroll
      for (int r = 0; r < 4; ++r)
        cst[(size_t)(seq0 + mt * 16 + q * 4 + r) * H_ + w * 32 + jt * 16 + cI] = cs[mt][jt][r];
}

// ---------------------------------------------------------------------------
// Outer decoder, MFMA. W_hh + xw register-resident; double-buffered h ->
// single lgkm-only barrier per step; rec stores drain in the background.
// ---------------------------------------------------------------------------
__global__ __launch_bounds__(512, 2) void k_outer_dec_mfma(
    const v8h* __restrict__ wpack,  // [4][32][64] v8h
    const float* __restrict__ xw,   // [3200][512] (biases folded)
    float* __restrict__ rec) {      // [3200*24][128] fp32
  __shared__ __align__(16) _Float16 ah[2][32][136];
  const int tid = threadIdx.x;
  const int w = tid >> 6;
  const int lane = tid & 63;
  const int cI = lane & 15;
  const int q = lane >> 4;
  const int seq0 = blockIdx.x * 32;

  v8h Bf[4][4];  // [kc][g]
#pragma unroll
  for (int kc = 0; kc < 4; ++kc)
#pragma unroll
    for (int g = 0; g < 4; ++g)
      Bf[kc][g] = wpack[(size_t)(kc * 32 + g * 8 + w) * 64 + lane];

  float xwr[2][4][4];
#pragma unroll
  for (int mt = 0; mt < 2; ++mt)
#pragma unroll
    for (int r = 0; r < 4; ++r) {
      int row = seq0 + mt * 16 + q * 4 + r;
#pragma unroll
      for (int g = 0; g < 4; ++g)
        xwr[mt][r][g] = xw[(size_t)row * 512 + g * 128 + w * 16 + cI];
    }

  for (int i = tid; i < 32 * 128; i += 512) ah[0][i >> 7][i & 127] = (_Float16)0.f;
  __syncthreads();

  float cs[2][4];
#pragma unroll
  for (int mt = 0; mt < 2; ++mt)
#pragma unroll
    for (int r = 0; r < 4; ++r) cs[mt][r] = 0.f;

  for (int t = 0; t < SEG_; ++t) {
    const int cb = t & 1, nb = cb ^ 1;
    v4f C[2][4];
#pragma unroll
    for (int mt = 0; mt < 2; ++mt)
#pragma unroll
      for (int g = 0; g < 4; ++g) {
        v4f z = {0.f, 0.f, 0.f, 0.f};
        C[mt][g] = z;
      }
#pragma unroll
    for (int kc = 0; kc < 4; ++kc) {
      v8h A0 = *(const v8h*)(&ah[cb][0 * 16 + cI][kc * 32 + q * 8]);
      v8h A1 = *(const v8h*)(&ah[cb][1 * 16 + cI][kc * 32 + q * 8]);
#pragma unroll
      for (int g = 0; g < 4; ++g) {
        C[0][g] = __builtin_amdgcn_mfma_f32_16x16x32_f16(A0, Bf[kc][g], C[0][g], 0, 0, 0);
        C[1][g] = __builtin_amdgcn_mfma_f32_16x16x32_f16(A1, Bf[kc][g], C[1][g], 0, 0, 0);
      }
    }
#pragma unroll
    for (int mt = 0; mt < 2; ++mt)
#pragma unroll
      for (int r = 0; r < 4; ++r) {
        float gi = sigm(C[mt][0][r] + xwr[mt][r][0]);
        float gf = sigm(C[mt][1][r] + xwr[mt][r][1]);
        float gg = tanh_f(C[mt][2][r] + xwr[mt][r][2]);
        float go = sigm(C[mt][3][r] + xwr[mt][r][3]);
        float cc = gf * cs[mt][r] + gi * gg;
        cs[mt][r] = cc;
        float h = go * tanh_f(cc);
        int row = mt * 16 + q * 4 + r;
        ah[nb][row][w * 16 + cI] = (_Float16)h;
        rec[((size_t)(seq0 + row) * SEG_ + t) * 128 + w * 16 + cI] = h;
      }
    BARRIER_LGKM();
  }
}

// ---------------------------------------------------------------------------
// Batched input projection: out[M][G] = A[M][256] @ wt2[128][G] + b1 + b2.
// ---------------------------------------------------------------------------
template <int GT>
__global__ __launch_bounds__(256) void k_proj(
    const float* __restrict__ A, const v2h* __restrict__ wt2,
    const float* __restrict__ b1, const float* __restrict__ b2,
    float* __restrict__ out) {
  constexpr int G = GT * 256;
  __shared__ __align__(16) _Float16 a2[16][256];
  const int tid = threadIdx.x;
  const size_t row0 = (size_t)blockIdx.x * 16;
  for (int idx = tid; idx < 16 * 256; idx += 256) {
    int r = idx >> 8, k = idx & 255;
    a2[r][k] = (_Float16)A[(row0 + (size_t)r) * 256 + k];
  }
  __syncthreads();
  float acc[16][GT];
#pragma unroll
  for (int r = 0; r < 16; ++r)
#pragma unroll
    for (int q = 0; q < GT; ++q) acc[r][q] = 0.f;
  const v2h* wp = wt2 + tid;
#pragma unroll 2
  for (int k2 = 0; k2 < 128; ++k2) {
    v2h w[GT];
#pragma unroll
    for (int q = 0; q < GT; ++q) w[q] = wp[256 * q];
    wp += G;
#pragma unroll
    for (int r = 0; r < 16; ++r) {
      v2h a = ((const v2h*)&a2[r][0])[k2];
#pragma unroll
      for (int q = 0; q < GT; ++q) acc[r][q] = fdot2f(w[q], a, acc[r][q]);
    }
  }
#pragma unroll
  for (int q = 0; q < GT; ++q) {
    float bias = b1[tid + 256 * q] + b2[tid + 256 * q];
#pragma unroll
    for (int r = 0; r < 16; ++r)
      out[(row0 + (size_t)r) * G + tid + 256 * q] = acc[r][q] + bias;
  }
}

// ---------------------------------------------------------------------------
// Inner LSTM: 1 block per batch element, 512 threads. Pair (2p,2p+1) owns
// h-index p, K split in half per lane. Weights: i,f,g rows (48 v8h) + first
// half of o-row (8 v8h) in VGPRs; second half of o in LDS (pitch 72 halves,
// uniform bank load). h double-buffered -> single lgkm barrier per step.
// Per-lane LDS reads/step: 16 (ah) + 8 (o) b128, down from 32.
// ---------------------------------------------------------------------------
__global__ __launch_bounds__(512, 2) void k_inner(
    const _Float16* __restrict__ whh,  // [1024][256] row-major f16
    const float* __restrict__ xw, long xw_seq_stride, long xw_t_stride, int T,
    float* __restrict__ h_out,   // [B*T][256] or nullptr
    float* __restrict__ c_out) { // [B][256] or nullptr
  __shared__ __align__(16) _Float16 ah[2][H_];
  __shared__ __align__(16) _Float16 wo[512 * 72];  // 8 v8h per lane, pitch 144B
  const int t_ = threadIdx.x;
  const int p = t_ >> 1;
  const int hf = t_ & 1;
  const int b = blockIdx.x;

  v8h wv[3][16];  // rows i,f,g ; this lane's 128-wide K-half
#pragma unroll
  for (int r = 0; r < 3; ++r) {
    const v8h* src = (const v8h*)(whh + ((size_t)(H_ * r + p)) * H_ + hf * 128);
#pragma unroll
    for (int q = 0; q < 16; ++q) wv[r][q] = src[q];
  }
  v8h wor[8];  // first 64 halves of o-slice in regs; rest to LDS
  {
    const v8h* src = (const v8h*)(whh + ((size_t)(H_ * 3 + p)) * H_ + hf * 128);
    v8h* dst = (v8h*)&wo[t_ * 72];
#pragma unroll
    for (int q = 0; q < 8; ++q) wor[q] = src[q];
#pragma unroll
    for (int q = 0; q < 8; ++q) dst[q] = src[8 + q];
  }
  if (t_ < H_) ah[0][t_] = (_Float16)0.f;
  float c = 0.f;
  __syncthreads();

  const bool cx = (xw_t_stride == 0);
  float x0 = 0.f, x1 = 0.f, x2 = 0.f, x3 = 0.f;
  if (cx) {
    const float* xwp = xw + (size_t)b * xw_seq_stride;
    x0 = xwp[p]; x1 = xwp[H_ + p]; x2 = xwp[2 * H_ + p]; x3 = xwp[3 * H_ + p];
  }

  for (int t = 0; t < T; ++t) {
    if (!cx) {
      const float* xwp = xw + (size_t)b * xw_seq_stride + (size_t)t * xw_t_stride;
      x0 = xwp[p]; x1 = xwp[H_ + p]; x2 = xwp[2 * H_ + p]; x3 = xwp[3 * H_ + p];
    }
    float a0 = 0.f, a1 = 0.f, a2 = 0.f, a3 = 0.f;
    const v8h* A8 = ((const v8h*)ah[t & 1]) + hf * 16;
    const v8h* O8 = (const v8h*)&wo[t_ * 72];
#pragma unroll
    for (int q = 0; q < 16; ++q) {
      v8h av = A8[q];
      v8h ov = (q < 8) ? wor[q] : O8[q - 8];
      v8h w0v = wv[0][q], w1v = wv[1][q], w2v = wv[2][q];
#pragma unroll
      for (int e = 0; e < 4; ++e) {
        v2h ap = ext8(av, e);
        a0 = fdot2f(ext8(w0v, e), ap, a0);
        a1 = fdot2f(ext8(w1v, e), ap, a1);
        a2 = fdot2f(ext8(w2v, e), ap, a2);
        a3 = fdot2f(ext8(ov, e), ap, a3);
      }
    }
    a0 += __shfl_xor(a0, 1);
    a1 += __shfl_xor(a1, 1);
    a2 += __shfl_xor(a2, 1);
    a3 += __shfl_xor(a3, 1);
    float gi = sigm(a0 + x0);
    float gf = sigm(a1 + x1);
    float gg = tanh_f(a2 + x2);
    float go = sigm(a3 + x3);
    c = gf * c + gi * gg;
    float h = go * tanh_f(c);
    if (hf == 0) {
      ah[(t + 1) & 1][p] = (_Float16)h;  // other buffer: no pre-write barrier
      if (h_out) h_out[((size_t)b * T + t) * H_ + p] = h;
    }
    BARRIER_LGKM();  // h(t) visible before step t+1 reads it
  }
  if (c_out && hf == 0) c_out[(size_t)b * H_ + p] = c;
}

// ---------------------------------------------------------------------------
extern "C" void kernel_launch(void* const* d_in, const int* in_sizes, int n_in,
                              void* d_out, int out_size, void* d_ws, size_t ws_size,
                              hipStream_t stream) {
  const float* inp    = (const float*)d_in[0];
  const float* oe_wih = (const float*)d_in[1];
  const float* oe_whh = (const float*)d_in[2];
  const float* oe_bih = (const float*)d_in[3];
  const float* oe_bhh = (const float*)d_in[4];
  const float* ie_wih = (const float*)d_in[5];
  const float* ie_whh = (const float*)d_in[6];
  const float* ie_bih = (const float*)d_in[7];
  const float* ie_bhh = (const float*)d_in[8];
  const float* id_wih = (const float*)d_in[9];
  const float* id_whh = (const float*)d_in[10];
  const float* id_bih = (const float*)d_in[11];
  const float* id_bhh = (const float*)d_in[12];
  const float* od_wih = (const float*)d_in[13];
  const float* od_whh = (const float*)d_in[14];
  const float* od_bih = (const float*)d_in[15];
  const float* od_bhh = (const float*)d_in[16];

  char* ws = (char*)d_ws;
  _Float16* xT     = (_Float16*)(ws + 0);         // 76800*128 f16 = 19,660,800
  v8h* wpack_oe    = (v8h*)(ws + 19660800);       // 12*64*64*16  =    786,432
  float* cst       = (float*)(ws + 20447232);     // 3200*256*4   =  3,276,800
  v2h* wt2_ie      = (v2h*)(ws + 23724032);       // 128*1024*4   =    524,288
  float* xw_ie     = (float*)(ws + 24248320);     // 3200*1024*4  = 13,107,200
  _Float16* whh_ie = (_Float16*)(ws + 37355520);  // 262144 f16   =    524,288
  float* bott      = (float*)(ws + 37879808);     // 32*256*4     =     32,768
  v2h* wt2_id      = (v2h*)(ws + 37912576);       //              =    524,288
  float* xw_id     = (float*)(ws + 38436864);     // 32*1024*4    =    131,072
  _Float16* whh_id = (_Float16*)(ws + 38567936);  //              =    524,288
  float* dec       = (float*)(ws + 39092224);     // 3200*256*4   =  3,276,800
  v2h* wt2_odih    = (v2h*)(ws + 42369024);       // 128*512*4    =    262,144
  float* xw_od     = (float*)(ws + 42631168);     // 3200*512*4   =  6,553,600
  v8h* wpack_od    = (v8h*)(ws + 49184768);       // 4*32*64*16   =    131,072
  float* rec       = (float*)(ws + 49315840);     // 76800*128*4  = 39,321,600  (end 88.6 MB)

  // --- weight prep ---
  k_wpack_oe<<<dim3(192), dim3(256), 0, stream>>>(wpack_oe, oe_wih, oe_whh);
  k_wt2<<<dim3(512), dim3(256), 0, stream>>>(wt2_ie, ie_wih, 256, nullptr, 0, 1024, 128 * 1024);
  k_wt2<<<dim3(512), dim3(256), 0, stream>>>(wt2_id, id_wih, 256, nullptr, 0, 1024, 128 * 1024);
  k_wt2<<<dim3(256), dim3(256), 0, stream>>>(wt2_odih, od_wih, 256, nullptr, 0, 512, 128 * 512);
  k_wpack_od<<<dim3(32), dim3(256), 0, stream>>>(wpack_od, od_whh);
  k_f16<<<dim3(1024), dim3(256), 0, stream>>>(whh_ie, ie_whh, 262144);
  k_f16<<<dim3(1024), dim3(256), 0, stream>>>(whh_id, id_whh, 262144);

  // --- pipeline ---
  k_tin<<<dim3(75, 4, 32), dim3(32, 8), 0, stream>>>(inp, xT);
  k_outer_enc_mfma<<<dim3(100), dim3(512), 0, stream>>>(wpack_oe, xT, oe_bih, oe_bhh, cst);
  k_proj<4><<<dim3(200), dim3(256), 0, stream>>>(cst, wt2_ie, ie_bih, ie_bhh, xw_ie);
  k_inner<<<dim3(32), dim3(512), 0, stream>>>(whh_ie, xw_ie, (long)S_ * 1024, 1024, S_, nullptr, bott);
  k_proj<4><<<dim3(2), dim3(256), 0, stream>>>(bott, wt2_id, id_bih, id_bhh, xw_id);
  k_inner<<<dim3(32), dim3(512), 0, stream>>>(whh_id, xw_id, 1024, 0, S_, dec, nullptr);
  k_proj<2><<<dim3(200), dim3(256), 0, stream>>>(dec, wt2_odih, od_bih, od_bhh, xw_od);
  k_outer_dec_mfma<<<dim3(100), dim3(512), 0, stream>>>(wpack_od, xw_od, rec);
  k_tout<<<dim3(75, 4, 32), dim3(32, 8), 0, stream>>>(rec, (float*)d_out);

  (void)in_sizes; (void)n_in; (void)out_size; (void)ws_size;
}